// Round 9
// baseline (302.006 us; speedup 1.0000x reference)
//
#include <hip/hip_runtime.h>
#include <stdint.h>

// CapsuleLayer dynamic routing, MI355X. fp32 in/out.
// B=256, N=10, I=1152, D=16, K(Din)=8, ROUTINGS=3.
// R9: K1 = pure streamer (no reduction at all — every in-K1 reduce variant
// cost 30-50us). part0 computed directly from x,W in caps_s0 (sum_i u is a
// plain contraction). caps_o templated (unrolled partial loads).

#define BN 256
#define NN 10
#define II 1152
#define DD 16
#define KK 8
#define NT 18          // K1 i-tiles of 64
#define ST 6           // S0 i-chunks of 192
#define NP0 24         // S0 partials per b (6 chunks x 4 waves)
#define NCH 9          // sweep chunks of 128 i
#define CHI 128

typedef unsigned short ushort_t;
typedef unsigned int uint_t;

__device__ __forceinline__ float bflo(uint_t u) {
    union { uint_t i; float f; } v; v.i = u << 16; return v.f;
}
__device__ __forceinline__ float bfhi(uint_t u) {
    union { uint_t i; float f; } v; v.i = u & 0xffff0000u; return v.f;
}
__device__ __forceinline__ uint_t f2bf(float f) {  // RTNE bf16
    union { float f; uint_t i; } v; v.f = f;
    uint_t x = v.i;
    return (x + 0x7fffu + ((x >> 16) & 1u)) >> 16;
}

// ---------------- K1: pure u_hat streamer -----------------------------------
// block = (i-tile of 64, b-pair). 256 thr. lane = il*4+dq.
// thread: i = it*64 + wv*16 + il, d-quad dq, 2 b's. No LDS, no shfl.
__global__ __launch_bounds__(256) void caps_uhat(const float* __restrict__ xg,
                                                 const float* __restrict__ wg,
                                                 ushort_t* __restrict__ u,
                                                 int b0, int c2)
{
    const int tid = threadIdx.x;
    const int lane = tid & 63, wv = tid >> 6;
    const int dq = lane & 3, il = lane >> 2;
    const int it = blockIdx.x / c2;
    const int bl = (blockIdx.x % c2) * 2;
    const int i = it * 64 + wv * 16 + il;

    float xv[2][8];
#pragma unroll
    for (int bb = 0; bb < 2; ++bb) {
        const float4* xp = (const float4*)(xg + ((size_t)(b0 + bl + bb) * II + i) * KK);
        float4 x0 = xp[0], x1 = xp[1];
        xv[bb][0] = x0.x; xv[bb][1] = x0.y; xv[bb][2] = x0.z; xv[bb][3] = x0.w;
        xv[bb][4] = x1.x; xv[bb][5] = x1.y; xv[bb][6] = x1.z; xv[bb][7] = x1.w;
    }

#pragma unroll
    for (int n = 0; n < NN; ++n) {
        const float4* wp = (const float4*)(wg + (size_t)(n * II + i) * (DD * KK)) + dq * 8;
        float4 w[8];
#pragma unroll
        for (int j = 0; j < 8; ++j) w[j] = wp[j];

#pragma unroll
        for (int bb = 0; bb < 2; ++bb) {
            float s[4];
#pragma unroll
            for (int dj = 0; dj < 4; ++dj) {
                float4 wa = w[2 * dj], wb = w[2 * dj + 1];
                s[dj] = wa.x * xv[bb][0] + wa.y * xv[bb][1]
                      + wa.z * xv[bb][2] + wa.w * xv[bb][3]
                      + wb.x * xv[bb][4] + wb.y * xv[bb][5]
                      + wb.z * xv[bb][6] + wb.w * xv[bb][7];
            }
            uint2 q;
            q.x = f2bf(s[0]) | (f2bf(s[1]) << 16);
            q.y = f2bf(s[2]) | (f2bf(s[3]) << 16);
            *(uint2*)(u + (((size_t)(bl + bb) * NN + n) * II + i) * DD + dq * 4) = q;
        }
    }
}

// ---------------- S0: part0 = 0.1 * sum_i u, computed straight from x,W -----
// block = (i-chunk of 192, b-pair). thread (il,dq) serially does 3 i-subtiles,
// acc[2][10][4] in regs, ONE butterfly at the end. partial per (block, wave).
__global__ __launch_bounds__(256) void caps_s0(const float* __restrict__ xg,
                                               const float* __restrict__ wg,
                                               float* __restrict__ part0,
                                               int b0, int c2)
{
    const int tid = threadIdx.x;
    const int lane = tid & 63, wv = tid >> 6;
    const int dq = lane & 3, il = lane >> 2;
    const int it = blockIdx.x / c2;
    const int bl = (blockIdx.x % c2) * 2;

    float acc[2][NN][4];
#pragma unroll
    for (int bb = 0; bb < 2; ++bb)
#pragma unroll
        for (int n = 0; n < NN; ++n)
#pragma unroll
            for (int dj = 0; dj < 4; ++dj) acc[bb][n][dj] = 0.f;

    for (int s = 0; s < 3; ++s) {
        const int i = it * 192 + s * 64 + wv * 16 + il;
        float xv[2][8];
#pragma unroll
        for (int bb = 0; bb < 2; ++bb) {
            const float4* xp = (const float4*)(xg + ((size_t)(b0 + bl + bb) * II + i) * KK);
            float4 x0 = xp[0], x1 = xp[1];
            xv[bb][0] = x0.x; xv[bb][1] = x0.y; xv[bb][2] = x0.z; xv[bb][3] = x0.w;
            xv[bb][4] = x1.x; xv[bb][5] = x1.y; xv[bb][6] = x1.z; xv[bb][7] = x1.w;
        }
#pragma unroll
        for (int n = 0; n < NN; ++n) {
            const float4* wp = (const float4*)(wg + (size_t)(n * II + i) * (DD * KK)) + dq * 8;
            float4 w[8];
#pragma unroll
            for (int j = 0; j < 8; ++j) w[j] = wp[j];
#pragma unroll
            for (int dj = 0; dj < 4; ++dj) {
                float4 wa = w[2 * dj], wb = w[2 * dj + 1];
#pragma unroll
                for (int bb = 0; bb < 2; ++bb) {
                    acc[bb][n][dj] += wa.x * xv[bb][0] + wa.y * xv[bb][1]
                                    + wa.z * xv[bb][2] + wa.w * xv[bb][3]
                                    + wb.x * xv[bb][4] + wb.y * xv[bb][5]
                                    + wb.z * xv[bb][6] + wb.w * xv[bb][7];
                }
            }
        }
    }
    // one simple butterfly over il (lane bits 2..5)
#pragma unroll
    for (int m = 4; m <= 32; m <<= 1)
#pragma unroll
        for (int bb = 0; bb < 2; ++bb)
#pragma unroll
            for (int n = 0; n < NN; ++n)
#pragma unroll
                for (int dj = 0; dj < 4; ++dj)
                    acc[bb][n][dj] += __shfl_xor(acc[bb][n][dj], m, 64);
    if (lane < 4) {  // lane == dq
#pragma unroll
        for (int bb = 0; bb < 2; ++bb)
#pragma unroll
            for (int n = 0; n < NN; ++n)
#pragma unroll
                for (int dj = 0; dj < 4; ++dj)
                    part0[((size_t)(b0 + bl + bb) * NP0 + it * 4 + wv) * 160
                          + n * 16 + dq * 4 + dj] = 0.1f * acc[bb][n][dj];
    }
}

// ---------------- caps_o<NP>: o[b] (+)= squash(sum_p part[b][p]) ------------
// grid c x 192. mode 0: o = squash(sum); 1: o += squash(sum).
template <int NP>
__global__ __launch_bounds__(192) void caps_o(const float* __restrict__ part,
                                              float* __restrict__ o,
                                              int b0, int mode)
{
    const int b = b0 + blockIdx.x;
    const int t = threadIdx.x;
    if (t < 160) {
        float v = 0.f;
#pragma unroll
        for (int p = 0; p < NP; ++p)
            v += part[((size_t)b * NP + p) * 160 + t];
        float sq = v * v;
#pragma unroll
        for (int m = 1; m <= 8; m <<= 1) sq += __shfl_xor(sq, m, 64);
        float val = v * (sqrtf(sq) / (1.0f + sq));
        if (mode) o[(size_t)b * 160 + t] += val;
        else      o[(size_t)b * 160 + t]  = val;
    }
}

// ---------------- sweep r=1,2 ----------------------------------------------
__global__ __launch_bounds__(256) void caps_sweep(const ushort_t* __restrict__ u,
                                                  const float* __restrict__ og,
                                                  float* __restrict__ pout, int b0)
{
    __shared__ float red[4 * 160];
    __shared__ float o_s[160];
    const int tid = threadIdx.x, g = tid >> 2, ld = tid & 3;
    const int cb = blockIdx.x / NCH, ch = blockIdx.x % NCH;
    const int b = b0 + cb;
    const ushort_t* ub = u + (size_t)cb * (NN * II * DD);

    const int i0 = ch * CHI + g;
    uint2 r0[NN], r1[NN];
#pragma unroll
    for (int n = 0; n < NN; ++n) {
        r0[n] = *(const uint2*)(ub + ((size_t)(n * II + i0)) * DD + ld * 4);
        r1[n] = *(const uint2*)(ub + ((size_t)(n * II + i0 + 64)) * DD + ld * 4);
    }
    if (tid < 160) o_s[tid] = og[(size_t)b * 160 + tid];
    __syncthreads();

    float sp[NN][4];
#pragma unroll
    for (int n = 0; n < NN; ++n)
#pragma unroll
        for (int j = 0; j < 4; ++j) sp[n][j] = 0.f;

#pragma unroll
    for (int step = 0; step < 2; ++step) {
        float p[NN];
#pragma unroll
        for (int n = 0; n < NN; ++n) {
            uint2 r = step ? r1[n] : r0[n];
            float4 o4 = *(const float4*)&o_s[(n << 4) + (ld << 2)];
            p[n] = bflo(r.x) * o4.x + bfhi(r.x) * o4.y
                 + bflo(r.y) * o4.z + bfhi(r.y) * o4.w;
        }
        float a[NN];
#pragma unroll
        for (int n = 0; n < NN; ++n) {
            float t2 = p[n] + __shfl_xor(p[n], 1, 64);
            a[n] = t2 + __shfl_xor(t2, 2, 64);
        }
        float m = a[0];
#pragma unroll
        for (int n = 1; n < NN; ++n) m = fmaxf(m, a[n]);
        float c[NN], ssum = 0.f;
#pragma unroll
        for (int n = 0; n < NN; ++n) { c[n] = __expf(a[n] - m); ssum += c[n]; }
        float inv = 1.0f / ssum;
#pragma unroll
        for (int n = 0; n < NN; ++n) {
            uint2 r = step ? r1[n] : r0[n];
            float w = c[n] * inv;
            sp[n][0] += w * bflo(r.x); sp[n][1] += w * bfhi(r.x);
            sp[n][2] += w * bflo(r.y); sp[n][3] += w * bfhi(r.y);
        }
    }

    // simple block reduce (proven R5 behavior)
#pragma unroll
    for (int m = 4; m <= 32; m <<= 1)
#pragma unroll
        for (int n = 0; n < NN; ++n)
#pragma unroll
            for (int j = 0; j < 4; ++j)
                sp[n][j] += __shfl_xor(sp[n][j], m, 64);
    const int lane = tid & 63, wv = tid >> 6;
    if (lane < 4) {
#pragma unroll
        for (int n = 0; n < NN; ++n)
#pragma unroll
            for (int j = 0; j < 4; ++j)
                red[(wv * NN + n) * 16 + ld * 4 + j] = sp[n][j];
    }
    __syncthreads();
    if (tid < 160) {
        int n = tid >> 4, dd = tid & 15;
        float v = 0.f;
#pragma unroll
        for (int w = 0; w < 4; ++w) v += red[(w * NN + n) * 16 + dd];
        pout[((size_t)b * NCH + ch) * 160 + tid] = v;
    }
}

extern "C" void kernel_launch(void* const* d_in, const int* in_sizes, int n_in,
                              void* d_out, int out_size, void* d_ws, size_t ws_size,
                              hipStream_t stream)
{
    const float* xg = (const float*)d_in[0];  // [B,I,K]
    const float* wg = (const float*)d_in[1];  // [N,I,D,K]
    if (n_in >= 2 && in_sizes[0] == NN * II * DD * KK) {
        const float* t = xg; xg = wg; wg = t;
    }
    float* outp = (float*)d_out;

    const size_t perB = (size_t)NN * II * DD * 2;        // 368,640 B bf16 u per b
    const size_t p0B  = (size_t)BN * NP0 * 160 * 4;      // 3,932,160
    const size_t p12B = (size_t)BN * NCH * 160 * 4;      // 1,474,560 each
    const size_t oB   = (size_t)BN * 160 * 4;            // 163,840
    size_t extra = p0B + 2 * p12B + oB;
    size_t avail = (ws_size > extra) ? ws_size - extra : 0;
    int C = 256;
    if (avail < (size_t)256 * perB) {
        C = (int)(avail / perB);
        C &= ~15;
        if (C < 16) C = 16;
    }
    ushort_t* uws = (ushort_t*)d_ws;
    float* part0 = (float*)((char*)d_ws + (size_t)C * perB);
    float* part1 = part0 + (size_t)BN * NP0 * 160;
    float* part2 = part1 + (size_t)BN * NCH * 160;
    float* ovec  = part2 + (size_t)BN * NCH * 160;

    for (int b0 = 0; b0 < BN; b0 += C) {
        int c = (BN - b0 < C) ? (BN - b0) : C;
        int c2 = c / 2;
        caps_uhat   <<<NT * c2, 256, 0, stream>>>(xg, wg, uws, b0, c2);
        caps_s0     <<<ST * c2, 256, 0, stream>>>(xg, wg, part0, b0, c2);
        caps_o<NP0> <<<c, 192, 0, stream>>>(part0, ovec, b0, 0);
        caps_sweep  <<<c * NCH, 256, 0, stream>>>(uws, ovec, part1, b0);
        caps_o<NCH> <<<c, 192, 0, stream>>>(part1, ovec, b0, 1);
        caps_sweep  <<<c * NCH, 256, 0, stream>>>(uws, ovec, part2, b0);
        caps_o<NCH> <<<c, 192, 0, stream>>>(part2, outp, b0, 0);
    }
}